// Round 2
// baseline (313.344 us; speedup 1.0000x reference)
//
#include <hip/hip_runtime.h>

// Flash attention, Q=K=V=x, row-mask. B=8, S=2048, D=512, fp32 in/out.
// S^T formulation: per wave 16 q-rows, per iter BN=32 j-rows.
// LDS: Kt[32][512] bf16 (row-XOR-swizzled) + xT[512][32] bf16 (transposed).
// R1 fix: defer-max rescale must scale acc rows (q=4g+r) by THAT row's sc,
// shuffled from lane 4g+r — not the lane's own sc (q=ln).

constexpr int BATCH = 8;
constexpr int SEQ   = 2048;
constexpr int DIM   = 512;
constexpr int BM    = 64;           // q-rows per block (4 waves x 16)
constexpr int BN    = 32;           // j-rows per tile
constexpr int NIT   = SEQ / BN;     // 64
constexpr float NEGV = -1e9f;
constexpr float THR  = 8.0f;        // defer-max rescale threshold (T13)

typedef float f4    __attribute__((ext_vector_type(4)));
typedef float f32x4 __attribute__((ext_vector_type(4)));
typedef short s16x8 __attribute__((ext_vector_type(8)));
typedef unsigned u32x2 __attribute__((ext_vector_type(2)));
typedef unsigned u32x4 __attribute__((ext_vector_type(4)));

__device__ __forceinline__ unsigned bfr(float x) {   // f32 -> bf16 (RNE)
    unsigned u = __float_as_uint(x);
    return (u + 0x7FFFu + ((u >> 16) & 1u)) >> 16;
}
__device__ __forceinline__ unsigned pk2(float a, float b) {
    return bfr(a) | (bfr(b) << 16);
}

__global__ __launch_bounds__(256, 1)
void attn_fwd(const float* __restrict__ x, const int* __restrict__ mask,
              float* __restrict__ out) {
    __shared__ __align__(16) unsigned char smem[65536]; // [0,32K)=Kt, [32K,64K)=xT

    const int tid  = threadIdx.x;
    const int w    = tid >> 6;        // wave 0..3
    const int lane = tid & 63;
    const int g    = lane >> 4;       // 4-lane-group 0..3
    const int ln   = lane & 15;

    const int batch = blockIdx.x & 7;         // XCD-pinned batch
    const int tile  = blockIdx.x >> 3;        // 0..31
    const int qbase = tile * BM + w * 16;

    const float* xb = x + (size_t)batch * SEQ * DIM;
    const f4*    xv = (const f4*)xb;

    // ---- Q fragments: row = qbase+ln, k-chunk kk: cols kk*32 + g*8 + e ----
    s16x8 qf[16];
    {
        const size_t qrow = (size_t)(qbase + ln);
        #pragma unroll
        for (int kk = 0; kk < 16; ++kk) {
            f4 a = xv[qrow * 128 + kk * 8 + g * 2];
            f4 b = xv[qrow * 128 + kk * 8 + g * 2 + 1];
            union { unsigned u[4]; s16x8 v; } F;
            F.u[0] = pk2(a[0], a[1]); F.u[1] = pk2(a[2], a[3]);
            F.u[2] = pk2(b[0], b[1]); F.u[3] = pk2(b[2], b[3]);
            qf[kk] = F.v;
        }
    }
    const bool rmask = (mask[(size_t)batch * SEQ + qbase + ln] == 0);

    f32x4 acc[32];
    #pragma unroll
    for (int i = 0; i < 32; ++i) acc[i] = (f32x4){0.f, 0.f, 0.f, 0.f};
    float m_run = NEGV;
    float l_run = 0.f;

    // staging maps
    const int cb  = tid & 127;   // Kt pass: 4-float col block
    const int rb0 = tid >> 7;    // Kt pass: 0..1
    const int dB  = tid >> 2;    // xT pass: d base 0..63
    const int jc  = tid & 3;     // xT pass: 8-row j chunk

    for (int jt = 0; jt < NIT; ++jt) {
        const int j0 = jt * BN;

        // ---- stage Kt[32][512] bf16, byte = jl*1024 + 2*col, XOR (jl&7)<<4 ----
        #pragma unroll
        for (int p = 0; p < 4; ++p) {
            const int rb = rb0 + 2 * p;              // 0..7
            #pragma unroll
            for (int jr = 0; jr < 4; ++jr) {
                const int jl = rb * 4 + jr;
                f4 v = xv[(size_t)(j0 + jl) * 128 + cb];
                u32x2 u;
                u[0] = pk2(v[0], v[1]);
                u[1] = pk2(v[2], v[3]);
                int a = jl * 1024 + cb * 8;
                a ^= (jl & 7) << 4;
                *(u32x2*)(smem + a) = u;
            }
        }
        // ---- stage xT[512][32] bf16 (transposed), byte = 32768 + d*64 + 2*j ----
        #pragma unroll
        for (int p = 0; p < 8; ++p) {
            const int d = dB + p * 64;               // 0..511
            const size_t gb = (size_t)(j0 + jc * 8) * DIM + d;
            float f0 = xb[gb + 0 * DIM], f1 = xb[gb + 1 * DIM];
            float f2 = xb[gb + 2 * DIM], f3 = xb[gb + 3 * DIM];
            float f4_ = xb[gb + 4 * DIM], f5 = xb[gb + 5 * DIM];
            float f6 = xb[gb + 6 * DIM], f7 = xb[gb + 7 * DIM];
            u32x4 t;
            t[0] = pk2(f0, f1); t[1] = pk2(f2, f3);
            t[2] = pk2(f4_, f5); t[3] = pk2(f6, f7);
            *(u32x4*)(smem + 32768 + d * 64 + jc * 16) = t;
        }
        __syncthreads();

        // ---- S^T = K · Q^T : two 16x16 j-subtiles, k over D=512 ----
        f32x4 s0 = (f32x4){0.f, 0.f, 0.f, 0.f};
        f32x4 s1 = (f32x4){0.f, 0.f, 0.f, 0.f};
        {
            const int jlA = ln;              // subtile 0 row
            const int jlB = 16 + ln;         // subtile 1 row ((16+ln)&7 == ln&7)
            const int sw  = (ln & 7) << 4;
            #pragma unroll
            for (int kk = 0; kk < 16; ++kk) {
                const int col = kk * 64 + g * 16;
                s16x8 k0 = *(const s16x8*)(smem + ((jlA * 1024 + col) ^ sw));
                s16x8 k1 = *(const s16x8*)(smem + ((jlB * 1024 + col) ^ sw));
                s0 = __builtin_amdgcn_mfma_f32_16x16x32_bf16(k0, qf[kk], s0, 0, 0, 0);
                s1 = __builtin_amdgcn_mfma_f32_16x16x32_bf16(k1, qf[kk], s1, 0, 0, 0);
            }
        }
        // row-mask: q = ln masked -> all its scores are exactly -1e9
        if (rmask) {
            s0 = (f32x4){NEGV, NEGV, NEGV, NEGV};
            s1 = (f32x4){NEGV, NEGV, NEGV, NEGV};
        }

        // ---- online softmax over j (per q = ln; lanes ln,ln+16,ln+32,ln+48) ----
        float t0 = fmaxf(fmaxf(s0[0], s0[1]), fmaxf(s0[2], s0[3]));
        float t1 = fmaxf(fmaxf(s1[0], s1[1]), fmaxf(s1[2], s1[3]));
        float tmax = fmaxf(t0, t1);
        tmax = fmaxf(tmax, __shfl_xor(tmax, 16));
        tmax = fmaxf(tmax, __shfl_xor(tmax, 32));

        if (__any(tmax > m_run + THR)) {     // defer-max: rare (diag tile only)
            const float mn = fmaxf(m_run, tmax);
            const float sc = __expf(m_run - mn);   // for q = ln
            l_run *= sc;
            m_run = mn;
            // acc rows are q = 4g+r -> need THAT row's sc (quad-consistent src)
            const float sc0 = __shfl(sc, 4 * g + 0);
            const float sc1 = __shfl(sc, 4 * g + 1);
            const float sc2 = __shfl(sc, 4 * g + 2);
            const float sc3 = __shfl(sc, 4 * g + 3);
            #pragma unroll
            for (int i = 0; i < 32; ++i) {
                acc[i][0] *= sc0;
                acc[i][1] *= sc1;
                acc[i][2] *= sc2;
                acc[i][3] *= sc3;
            }
        }

        const float p0 = __expf(s0[0] - m_run), p1 = __expf(s0[1] - m_run);
        const float p2 = __expf(s0[2] - m_run), p3 = __expf(s0[3] - m_run);
        const float p4 = __expf(s1[0] - m_run), p5 = __expf(s1[1] - m_run);
        const float p6 = __expf(s1[2] - m_run), p7 = __expf(s1[3] - m_run);

        float ps = ((p0 + p1) + (p2 + p3)) + ((p4 + p5) + (p6 + p7));
        ps += __shfl_xor(ps, 16);
        ps += __shfl_xor(ps, 32);
        l_run += ps;

        // ---- redistribute P (q=ln, j=sub*16+4g'+r) -> PV A-frag (q=ln, j=8g+e) ----
        const int pk00 = (int)pk2(p0, p1), pk01 = (int)pk2(p2, p3);
        const int pk10 = (int)pk2(p4, p5), pk11 = (int)pk2(p6, p7);
        const int src0 = ln + ((g & 1) << 5);
        const int src1 = src0 + 16;
        const int a00 = __shfl(pk00, src0), a01 = __shfl(pk10, src0);
        const int b00 = __shfl(pk01, src0), b01 = __shfl(pk11, src0);
        const int a10 = __shfl(pk00, src1), a11 = __shfl(pk10, src1);
        const int b10 = __shfl(pk01, src1), b11 = __shfl(pk11, src1);
        union { int u[4]; s16x8 v; } PA;
        const bool hi = (g & 2);
        PA.u[0] = hi ? a01 : a00;
        PA.u[1] = hi ? b01 : b00;
        PA.u[2] = hi ? a11 : a10;
        PA.u[3] = hi ? b11 : b10;

        // ---- O += P @ V : B-frag from xT (d = dt*16+ln, j = 8g+e contiguous) ----
        #pragma unroll
        for (int dt = 0; dt < 32; ++dt) {
            const int d = dt * 16 + ln;
            s16x8 vf = *(const s16x8*)(smem + 32768 + d * 64 + g * 16);
            acc[dt] = __builtin_amdgcn_mfma_f32_16x16x32_bf16(PA.v, vf, acc[dt], 0, 0, 0);
        }
        __syncthreads();
    }

    // ---- epilogue: O[q][d] = acc / l ; acc rows are q = 4g+r, l is per q=ln ----
    const float inv = 1.0f / l_run;
    const float i0 = __shfl(inv, 4 * g + 0);
    const float i1 = __shfl(inv, 4 * g + 1);
    const float i2 = __shfl(inv, 4 * g + 2);
    const float i3 = __shfl(inv, 4 * g + 3);
    float* ob = out + ((size_t)batch * SEQ + qbase) * DIM;
    #pragma unroll
    for (int dt = 0; dt < 32; ++dt) {
        const int d = dt * 16 + ln;
        ob[(size_t)(4 * g + 0) * DIM + d] = acc[dt][0] * i0;
        ob[(size_t)(4 * g + 1) * DIM + d] = acc[dt][1] * i1;
        ob[(size_t)(4 * g + 2) * DIM + d] = acc[dt][2] * i2;
        ob[(size_t)(4 * g + 3) * DIM + d] = acc[dt][3] * i3;
    }
}

extern "C" void kernel_launch(void* const* d_in, const int* in_sizes, int n_in,
                              void* d_out, int out_size, void* d_ws, size_t ws_size,
                              hipStream_t stream) {
    (void)in_sizes; (void)n_in; (void)d_ws; (void)ws_size; (void)out_size;
    const float* x    = (const float*)d_in[0];
    const int*   mask = (const int*)d_in[1];
    float*       out  = (float*)d_out;
    dim3 grid(BATCH * (SEQ / BM));   // 256 blocks = 1/CU, batch pinned per XCD
    dim3 block(256);                 // 4 waves
    attn_fwd<<<grid, block, 0, stream>>>(x, mask, out);
}

// Round 3
// 178.295 us; speedup vs baseline: 1.7574x; 1.7574x over previous
//
#include <hip/hip_runtime.h>

// Flash attention, Q=K=V=x, row-mask. B=8, S=2048, D=512, fp32 in/out.
// R3: prep kernel -> bf16 xbf[B][S][D] + xt[B][D][S] in d_ws;
//     global_load_lds staging (pre-swizzled source, linear LDS dest);
//     conflict-free read swizzles; double-buffer + counted vmcnt(16).

constexpr int BATCH = 8;
constexpr int SEQ   = 2048;
constexpr int DIM   = 512;
constexpr int BM    = 64;           // q-rows per block (4 waves x 16)
constexpr int BN    = 32;           // j-rows per tile
constexpr int NIT   = SEQ / BN;     // 64
constexpr float NEGV = -1e9f;
constexpr float THR  = 8.0f;        // defer-max rescale threshold (T13)

typedef float f4    __attribute__((ext_vector_type(4)));
typedef float f32x4 __attribute__((ext_vector_type(4)));
typedef short s16x8 __attribute__((ext_vector_type(8)));
typedef unsigned u32x2 __attribute__((ext_vector_type(2)));
typedef unsigned u32x4 __attribute__((ext_vector_type(4)));

#define AS1 __attribute__((address_space(1)))
#define AS3 __attribute__((address_space(3)))

__device__ __forceinline__ unsigned bfr(float x) {   // f32 -> bf16 (RNE)
    unsigned u = __float_as_uint(x);
    return (u + 0x7FFFu + ((u >> 16) & 1u)) >> 16;
}
__device__ __forceinline__ unsigned pk2(float a, float b) {
    return bfr(a) | (bfr(b) << 16);
}
__device__ __forceinline__ void gload_lds16(const void* g, void* l) {
    __builtin_amdgcn_global_load_lds((const AS1 void*)g, (AS3 void*)l, 16, 0, 0);
}

// ---------------- prep: fp32 -> bf16, row-major + transposed ----------------
__global__ __launch_bounds__(256)
void prep_kernel(const float* __restrict__ x, unsigned short* __restrict__ xbf,
                 unsigned short* __restrict__ xt) {
    __shared__ __align__(16) unsigned short tile[64 * 66];
    const int t   = threadIdx.x;
    const int bid = blockIdx.x;          // 2048 = 8 batches * 32 s-tiles * 8 d-tiles
    const int b   = bid >> 8;
    const int rr  = bid & 255;
    const int s0  = (rr >> 3) * 64;
    const int d0  = (rr & 7) * 64;
    const float* xb = x + (size_t)b * SEQ * DIM;

    const int sl = t >> 4, c4 = t & 15;
    #pragma unroll
    for (int k = 0; k < 4; ++k) {
        const int s = sl + k * 16;
        f4 v = *(const f4*)(xb + (size_t)(s0 + s) * DIM + d0 + c4 * 4);
        u32x2 p; p[0] = pk2(v[0], v[1]); p[1] = pk2(v[2], v[3]);
        *(u32x2*)(xbf + ((size_t)b * SEQ + s0 + s) * DIM + d0 + c4 * 4) = p;
        tile[(c4 * 4 + 0) * 66 + s] = (unsigned short)bfr(v[0]);
        tile[(c4 * 4 + 1) * 66 + s] = (unsigned short)bfr(v[1]);
        tile[(c4 * 4 + 2) * 66 + s] = (unsigned short)bfr(v[2]);
        tile[(c4 * 4 + 3) * 66 + s] = (unsigned short)bfr(v[3]);
    }
    __syncthreads();
    const int dl = t >> 2, sb = t & 3;
    const unsigned* lp = (const unsigned*)&tile[dl * 66 + sb * 16];
    unsigned short* op = xt + ((size_t)b * DIM + d0 + dl) * SEQ + s0 + sb * 16;
    u32x4 a, c;
    a[0] = lp[0]; a[1] = lp[1]; a[2] = lp[2]; a[3] = lp[3];
    c[0] = lp[4]; c[1] = lp[5]; c[2] = lp[6]; c[3] = lp[7];
    *(u32x4*)op = a;
    *(u32x4*)(op + 8) = c;
}

// ---------------- main attention kernel ----------------
__global__ __launch_bounds__(256, 1)
void attn_fwd(const unsigned short* __restrict__ xbf,
              const unsigned short* __restrict__ xt,
              const int* __restrict__ mask,
              float* __restrict__ out) {
    extern __shared__ __align__(16) char smem[];   // 2 x (Kt 32K + xT 32K) = 128K

    const int tid  = threadIdx.x;
    const int w    = tid >> 6;
    const int lane = tid & 63;
    const int g    = lane >> 4;
    const int ln   = lane & 15;

    const int batch = blockIdx.x & 7;
    const int tile  = blockIdx.x >> 3;
    const int qbase = tile * BM + w * 16;

    const char* xbf_b = (const char*)(xbf + (size_t)batch * SEQ * DIM);
    const char* xt_b  = (const char*)(xt + (size_t)batch * (size_t)DIM * SEQ);

    // Q fragments from bf16 xbf
    s16x8 qf[16];
    {
        const s16x8* qv = (const s16x8*)(xbf_b + (size_t)(qbase + ln) * 1024);
        #pragma unroll
        for (int kk = 0; kk < 16; ++kk) qf[kk] = qv[kk * 4 + g];
    }
    const bool rmask = (mask[(size_t)batch * SEQ + qbase + ln] == 0);

    f32x4 acc[32];
    #pragma unroll
    for (int i = 0; i < 32; ++i) acc[i] = (f32x4){0.f, 0.f, 0.f, 0.f};
    float m_run = NEGV;
    float l_run = 0.f;

    // staging bases
    const int ls4 = lane << 4;
    // xT per-lane source base: d = dbase + (lane>>2), j-slot ((lane&3) ^ ((lane>>3)&3))
    const char* vbl = xt_b + (size_t)(lane >> 2) * 4096
                    + (((lane & 3) ^ ((lane >> 3) & 3)) << 4)
                    + (size_t)w * 524288;            // w*128 d-rows * 4096B

    auto stagef = [&](int q, int jts) {
        char* bK = smem + (q << 16);
        char* bV = bK + 32768;
        const int j0s = jts * BN;
        #pragma unroll
        for (int r = 0; r < 8; ++r) {
            // LDS row w*8+r linear; source granule pre-XORed by r (= row&7)
            gload_lds16(xbf_b + (size_t)(j0s + w * 8 + r) * 1024 + (ls4 ^ (r << 4)),
                        bK + (w * 8 + r) * 1024);
        }
        #pragma unroll
        for (int i = 0; i < 8; ++i) {
            gload_lds16(vbl + (size_t)i * 65536 + j0s * 2,
                        bV + w * 8192 + i * 1024);
        }
    };

    stagef(0, 0);

    for (int jt = 0; jt < NIT; ++jt) {
        const int cur = jt & 1;
        if (jt + 1 < NIT) {
            stagef(cur ^ 1, jt + 1);
            asm volatile("s_waitcnt vmcnt(16)" ::: "memory"); // tile jt landed
        } else {
            asm volatile("s_waitcnt vmcnt(0)" ::: "memory");
        }
        __builtin_amdgcn_sched_barrier(0);
        __builtin_amdgcn_s_barrier();
        asm volatile("" ::: "memory");

        char* bK = smem + (cur << 16);
        char* bV = bK + 32768;

        // ---- S^T = K · Q^T ----
        f32x4 s0 = (f32x4){0.f, 0.f, 0.f, 0.f};
        f32x4 s1 = (f32x4){0.f, 0.f, 0.f, 0.f};
        {
            const int swz = (ln & 7) << 4;
            const int cb0 = ln * 1024 + g * 16;
            #pragma unroll
            for (int kk = 0; kk < 16; ++kk) {
                const int off = (cb0 + kk * 64) ^ swz;
                s16x8 k0 = *(const s16x8*)(bK + off);
                s16x8 k1 = *(const s16x8*)(bK + off + 16384);
                s0 = __builtin_amdgcn_mfma_f32_16x16x32_bf16(k0, qf[kk], s0, 0, 0, 0);
                s1 = __builtin_amdgcn_mfma_f32_16x16x32_bf16(k1, qf[kk], s1, 0, 0, 0);
            }
        }
        if (rmask) {
            s0 = (f32x4){NEGV, NEGV, NEGV, NEGV};
            s1 = (f32x4){NEGV, NEGV, NEGV, NEGV};
        }

        // ---- online softmax (per q = ln) ----
        float t0 = fmaxf(fmaxf(s0[0], s0[1]), fmaxf(s0[2], s0[3]));
        float t1 = fmaxf(fmaxf(s1[0], s1[1]), fmaxf(s1[2], s1[3]));
        float tmax = fmaxf(t0, t1);
        tmax = fmaxf(tmax, __shfl_xor(tmax, 16));
        tmax = fmaxf(tmax, __shfl_xor(tmax, 32));

        if (__any(tmax > m_run + THR)) {
            const float mn = fmaxf(m_run, tmax);
            const float sc = __expf(m_run - mn);   // for q = ln
            l_run *= sc;
            m_run = mn;
            const float sc0 = __shfl(sc, 4 * g + 0);
            const float sc1 = __shfl(sc, 4 * g + 1);
            const float sc2 = __shfl(sc, 4 * g + 2);
            const float sc3 = __shfl(sc, 4 * g + 3);
            #pragma unroll
            for (int i = 0; i < 32; ++i) {
                acc[i][0] *= sc0; acc[i][1] *= sc1;
                acc[i][2] *= sc2; acc[i][3] *= sc3;
            }
        }

        const float p0 = __expf(s0[0] - m_run), p1 = __expf(s0[1] - m_run);
        const float p2 = __expf(s0[2] - m_run), p3 = __expf(s0[3] - m_run);
        const float p4 = __expf(s1[0] - m_run), p5 = __expf(s1[1] - m_run);
        const float p6 = __expf(s1[2] - m_run), p7 = __expf(s1[3] - m_run);

        float ps = ((p0 + p1) + (p2 + p3)) + ((p4 + p5) + (p6 + p7));
        ps += __shfl_xor(ps, 16);
        ps += __shfl_xor(ps, 32);
        l_run += ps;

        // ---- redistribute P -> PV A-frag ----
        const int pk00 = (int)pk2(p0, p1), pk01 = (int)pk2(p2, p3);
        const int pk10 = (int)pk2(p4, p5), pk11 = (int)pk2(p6, p7);
        const int src0 = ln + ((g & 1) << 5);
        const int src1 = src0 + 16;
        const int a00 = __shfl(pk00, src0), a01 = __shfl(pk10, src0);
        const int b00 = __shfl(pk01, src0), b01 = __shfl(pk11, src0);
        const int a10 = __shfl(pk00, src1), a11 = __shfl(pk10, src1);
        const int b10 = __shfl(pk01, src1), b11 = __shfl(pk11, src1);
        union { int u[4]; s16x8 v; } PA;
        const bool hi = (g & 2);
        PA.u[0] = hi ? a01 : a00;
        PA.u[1] = hi ? b01 : b00;
        PA.u[2] = hi ? a11 : a10;
        PA.u[3] = hi ? b11 : b10;

        // ---- O += P @ V ; B-frag from xT LDS, sigma(d)=(ln>>1)&3 swizzle ----
        const char* vb = bV + ln * 64 + ((g ^ ((ln >> 1) & 3)) << 4);
        #pragma unroll
        for (int dt = 0; dt < 32; ++dt) {
            s16x8 vf = *(const s16x8*)(vb + dt * 1024);
            acc[dt] = __builtin_amdgcn_mfma_f32_16x16x32_bf16(PA.v, vf, acc[dt], 0, 0, 0);
        }
        asm volatile("" ::: "memory");
        __builtin_amdgcn_s_barrier();
    }

    // ---- epilogue ----
    const float inv = 1.0f / l_run;
    const float i0 = __shfl(inv, 4 * g + 0);
    const float i1 = __shfl(inv, 4 * g + 1);
    const float i2 = __shfl(inv, 4 * g + 2);
    const float i3 = __shfl(inv, 4 * g + 3);
    float* ob = out + ((size_t)batch * SEQ + qbase) * DIM;
    #pragma unroll
    for (int dt = 0; dt < 32; ++dt) {
        const int d = dt * 16 + ln;
        ob[(size_t)(4 * g + 0) * DIM + d] = acc[dt][0] * i0;
        ob[(size_t)(4 * g + 1) * DIM + d] = acc[dt][1] * i1;
        ob[(size_t)(4 * g + 2) * DIM + d] = acc[dt][2] * i2;
        ob[(size_t)(4 * g + 3) * DIM + d] = acc[dt][3] * i3;
    }
}

extern "C" void kernel_launch(void* const* d_in, const int* in_sizes, int n_in,
                              void* d_out, int out_size, void* d_ws, size_t ws_size,
                              hipStream_t stream) {
    (void)in_sizes; (void)n_in; (void)ws_size; (void)out_size;
    const float* x    = (const float*)d_in[0];
    const int*   mask = (const int*)d_in[1];
    float*       out  = (float*)d_out;
    unsigned short* xbf = (unsigned short*)d_ws;                       // 16 MiB
    unsigned short* xt  = xbf + (size_t)BATCH * SEQ * DIM;             // 16 MiB

    prep_kernel<<<dim3(2048), dim3(256), 0, stream>>>(x, xbf, xt);

    (void)hipFuncSetAttribute((const void*)attn_fwd,
                              hipFuncAttributeMaxDynamicSharedMemorySize, 131072);
    attn_fwd<<<dim3(256), dim3(256), 131072, stream>>>(xbf, xt, mask, out);
}